// Round 2
// baseline (520.648 us; speedup 1.0000x reference)
//
#include <hip/hip_runtime.h>
#include <math.h>
#include <stdint.h>

#define T_   512
#define H_   1024
#define I_   512
#define E_   64
#define K_   6
#define G_   8
#define TG_  3
#define EB_  80      // 64 routed + 16 shared-expert (half x token-eighth) blocks

typedef _Float16 h8 __attribute__((ext_vector_type(8)));
typedef _Float16 h4v __attribute__((ext_vector_type(4)));
typedef float    f4 __attribute__((ext_vector_type(4)));

// ---------------- router: sigmoid + group-limited top-k (verified) ------
__global__ __launch_bounds__(64) void router_k(
    const float* __restrict__ x, const float* __restrict__ gw,
    int* __restrict__ cnt, int* __restrict__ tlist, float* __restrict__ wlist)
{
  const int t   = blockIdx.x;
  const int tid = threadIdx.x;
  __shared__ float sx[H_];
  __shared__ float sc[E_];

  for (int h4 = tid; h4 < H_/4; h4 += 64)
    ((float4*)sx)[h4] = ((const float4*)(x + (size_t)t*H_))[h4];
  __syncthreads();

  const float* wr = gw + (size_t)tid * H_;
  float acc = 0.f;
  for (int h = 0; h < H_; h += 4) {
    float4 xv = *(const float4*)(sx + h);
    float4 wv = *(const float4*)(wr + h);
    acc = fmaf(xv.x, wv.x, acc); acc = fmaf(xv.y, wv.y, acc);
    acc = fmaf(xv.z, wv.z, acc); acc = fmaf(xv.w, wv.w, acc);
  }
  sc[tid] = 1.f / (1.f + expf(-acc));
  __syncthreads();

  if (tid == 0) {
    float gs[G_];
    #pragma unroll
    for (int g = 0; g < G_; g++) {
      float m = sc[g*8];
      #pragma unroll
      for (int j = 1; j < 8; j++) m = fmaxf(m, sc[g*8+j]);
      gs[g] = m;
    }
    unsigned gp = 0;
    for (int r = 0; r < TG_; r++) {
      int best = 0; float bv = -1e30f;
      for (int g = 0; g < G_; g++)
        if (!((gp >> g) & 1) && gs[g] > bv) { bv = gs[g]; best = g; }
      gp |= 1u << best;
    }
    int   eidx[K_]; float ew[K_];
    unsigned long long em = 0ull;
    float wsum = 0.f;
    for (int r = 0; r < K_; r++) {
      int best = 0; float bv = -1e30f;
      for (int e = 0; e < E_; e++) {
        if (!((gp >> (e >> 3)) & 1)) continue;
        if ((em >> e) & 1ull) continue;
        if (sc[e] > bv) { bv = sc[e]; best = e; }
      }
      em |= 1ull << best; eidx[r] = best; ew[r] = bv; wsum += bv;
    }
    const float inv = 2.5f / (wsum + 1e-20f);
    for (int r = 0; r < K_; r++) {
      int e = eidx[r];
      int pos = atomicAdd(&cnt[e], 1);
      tlist[e*T_ + pos] = (t << 13) | (t*K_ + r);   // hmid row = t*6+rank
      wlist[e*T_ + pos] = ew[r] * inv;
    }
  }
}

// ---------------- pseudo-expert token lists (shared halves) -------------
__global__ void pseudo_init_k(int* cnt, int* tlist, float* wlist) {
  int s = blockIdx.x*256 + threadIdx.x;       // 0..1023
  if (s == 0) { cnt[64] = T_; cnt[65] = T_; }
  if (s < 1024) {
    int e = 64 + (s >> 9);
    int t = s & 511;
    tlist[e*T_ + t] = (t << 13) | (3072 + s); // rows 3072..4095
    wlist[e*T_ + t] = 1.0f;
  }
}

// ---------------- x -> f16 prep ----------------------------------------
__global__ __launch_bounds__(256) void xh_prep_k(
    const float* __restrict__ x, _Float16* __restrict__ xh)
{
  int i = blockIdx.x*256 + threadIdx.x;       // float4 index
  float4 v = ((const float4*)x)[i];
  h4v o = { (_Float16)v.x, (_Float16)v.y, (_Float16)v.z, (_Float16)v.w };
  *(h4v*)(xh + (size_t)i*4) = o;
}

// ---- expert-block descriptor: eb<64 -> routed; eb>=64 -> shared slice ---
__device__ __forceinline__ void eb_decode(int eb, const int* cnt,
                                          int& e, int& lo, int& hi) {
  if (eb < E_) { e = eb; lo = 0; hi = cnt[e]; }
  else { int q = (eb - E_) & 7; e = E_ + ((eb - E_) >> 3); lo = q*64; hi = lo + 64; }
}

// async 16B global -> LDS (wave-uniform LDS base + lane*16 by HW)
__device__ __forceinline__ void gld16(const int* g, void* l) {
  __builtin_amdgcn_global_load_lds(
      (const __attribute__((address_space(1))) void*)g,
      (__attribute__((address_space(3))) void*)l, 16, 0, 0);
}

// two int4 (8 int32 weights) -> f16 fragment with scale folded
__device__ __forceinline__ h8 cvt8(int4 a, int4 b, float s) {
  union { _Float16 f[8]; h8 v; } t;
  t.f[0]=(_Float16)((float)a.x*s); t.f[1]=(_Float16)((float)a.y*s);
  t.f[2]=(_Float16)((float)a.z*s); t.f[3]=(_Float16)((float)a.w*s);
  t.f[4]=(_Float16)((float)b.x*s); t.f[5]=(_Float16)((float)b.y*s);
  t.f[6]=(_Float16)((float)b.z*s); t.f[7]=(_Float16)((float)b.w*s);
  return t.v;
}

#define WAITV8() do { asm volatile("s_waitcnt vmcnt(8)" ::: "memory"); \
                      __builtin_amdgcn_sched_barrier(0); } while (0)
#define WAITV4() do { asm volatile("s_waitcnt vmcnt(4)" ::: "memory"); \
                      __builtin_amdgcn_sched_barrier(0); } while (0)

// ---------------- gate+up MFMA: hmid[row, ic*64..+64) -------------------
// Barrier-free per-wave pipeline: each wave owns a private 3-deep LDS ring
// (tile = its 16 i-rows x 32 ints x {g,u} = 4KB), staged by global_load_lds,
// synced only by counted vmcnt (never 0). A-frags issued one tile early so
// compiler's positional waits never drain the ring. Chunk XOR swizzle
// (16B granule ^= row&7) on both stage-source and ds_read sides.
__global__ __launch_bounds__(256, 3) void gateup_k(
    const _Float16* __restrict__ xh,
    const int* __restrict__ wg, const float* __restrict__ sg,
    const int* __restrict__ wu, const float* __restrict__ su,
    const int* __restrict__ shwg, const float* __restrict__ shsg,
    const int* __restrict__ shwu, const float* __restrict__ shsu,
    const int* __restrict__ cnt, const int* __restrict__ tlist,
    const float* __restrict__ wlist,
    _Float16* __restrict__ hmid)
{
  const int ic = blockIdx.x;                  // i-chunk of 64
  const int eb = blockIdx.y;
  int e, lo, hi;
  eb_decode(eb, cnt, e, lo, hi);
  if (hi <= lo) return;

  const int tid  = threadIdx.x;
  const int lane = tid & 63;
  const int wv   = tid >> 6;
  const int mr   = lane & 15;
  const int quad = lane >> 4;

  const int *wgb, *wub; const float *sgp, *sup; int sib;
  if (e < E_) {
    wgb = wg + (size_t)e*I_*H_;  wub = wu + (size_t)e*I_*H_;
    sgp = sg + e*32;  sup = su + e*32;  sib = ic >> 1;
  } else {
    int hf = e - E_;
    wgb = shwg + (size_t)hf*512*H_;  wub = shwu + (size_t)hf*512*H_;
    sgp = shsg;  sup = shsu;  sib = hf*4 + (ic >> 1);
  }
  const int r0base = ic*64;

  __shared__ int lds[4*3*1024];               // 4 waves x ring3 x 4KB = 48KB
  int* wbase = lds + wv*3072;

  // constant per-lane staging addresses (row rl, swizzled 16B chunk)
  const int srl0 = wv*16 + (lane >> 3);       // rows group i=0 (0..7 of wave)
  const int srl1 = srl0 + 8;                  // rows group i=1
  const int sc0  = ((lane & 7) ^ (srl0 & 7)) * 4;
  const int sc1  = ((lane & 7) ^ (srl1 & 7)) * 4;
  const int* g_r0 = wgb + (size_t)(r0base + srl0)*H_ + sc0;
  const int* g_r1 = wgb + (size_t)(r0base + srl1)*H_ + sc1;
  const int* u_r0 = wub + (size_t)(r0base + srl0)*H_ + sc0;
  const int* u_r1 = wub + (size_t)(r0base + srl1)*H_ + sc1;

  auto stage = [&](int* d, int kt) {          // 4 gld16 = one 4KB wave-tile
    const int k4 = kt * 32;
    gld16(g_r0 + k4, d);
    gld16(g_r1 + k4, d + 256);
    gld16(u_r0 + k4, d + 512);
    gld16(u_r1 + k4, d + 768);
  };

  f4 accg[4], accu[4];
  const int ro = mr*32;
  const int c0 = ((quad*2    ) ^ (mr & 7)) * 4;
  const int c1 = ((quad*2 + 1) ^ (mr & 7)) * 4;

  auto compute = [&](const int* b, int kt, h8* A) {
    const float sg_ = sgp[sib*8 + (kt >> 2)];
    const float su_ = sup[sib*8 + (kt >> 2)];
    int4 g0 = *(const int4*)(b + ro + c0);
    int4 g1 = *(const int4*)(b + ro + c1);
    int4 u0 = *(const int4*)(b + 512 + ro + c0);
    int4 u1 = *(const int4*)(b + 512 + ro + c1);
    h8 bg = cvt8(g0, g1, sg_);
    h8 bu = cvt8(u0, u1, su_);
    #pragma unroll
    for (int mt = 0; mt < 4; mt++) {
      accg[mt] = __builtin_amdgcn_mfma_f32_16x16x32_f16(A[mt], bg, accg[mt], 0,0,0);
      accu[mt] = __builtin_amdgcn_mfma_f32_16x16x32_f16(A[mt], bu, accu[mt], 0,0,0);
    }
  };

#define GU_STEP(KT, BUFC, BUFS, AUSE, ALOAD)                                \
    WAITV8();                                                               \
    _Pragma("unroll")                                                       \
    for (int mt = 0; mt < 4; mt++)                                          \
      ALOAD[mt] = *(const h8*)(ax[mt] + ((KT)+1)*32);                       \
    stage(wbase + (BUFS)*1024, (KT)+2);                                     \
    compute(wbase + (BUFC)*1024, (KT), AUSE);

  for (int base = lo; base < hi; base += 64) {
    const _Float16* ax[4];
    #pragma unroll
    for (int mt = 0; mt < 4; mt++) {
      int sl = base + mt*16 + mr;
      int tok = (sl < hi) ? (tlist[e*T_ + sl] >> 13) : 0;
      ax[mt] = xh + (size_t)tok*H_ + quad*8;
    }
    #pragma unroll
    for (int mt = 0; mt < 4; mt++) { accg[mt] = (f4){0.f,0.f,0.f,0.f}; accu[mt] = accg[mt]; }

    h8 A0[4], A1[4];
    // prologue: stage(0), A(0), stage(1)  -> steady wait = vmcnt(8)
    stage(wbase, 0);
    #pragma unroll
    for (int mt = 0; mt < 4; mt++) A0[mt] = *(const h8*)(ax[mt]);
    stage(wbase + 1024, 1);

    for (int k6 = 0; k6 < 5; k6++) {          // kt = 0..29
      const int kt = k6*6;
      GU_STEP(kt+0, 0, 2, A0, A1)
      GU_STEP(kt+1, 1, 0, A1, A0)
      GU_STEP(kt+2, 2, 1, A0, A1)
      GU_STEP(kt+3, 0, 2, A1, A0)
      GU_STEP(kt+4, 1, 0, A0, A1)
      GU_STEP(kt+5, 2, 1, A1, A0)
    }
    // kt = 30 (buf0): no stage, load A(31)
    WAITV8();
    #pragma unroll
    for (int mt = 0; mt < 4; mt++) A1[mt] = *(const h8*)(ax[mt] + 31*32);
    compute(wbase, 30, A0);
    // kt = 31 (buf1)
    WAITV4();
    compute(wbase + 1024, 31, A1);

    // epilogue: silu(g)*u*w -> hmid   (C/D: col=lane&15 (i), row=quad*4+r)
    const int icol = ic*64 + wv*16 + mr;
    #pragma unroll
    for (int mt = 0; mt < 4; mt++) {
      #pragma unroll
      for (int r = 0; r < 4; r++) {
        int sl = base + mt*16 + quad*4 + r;
        if (sl < hi) {
          int   ent = tlist[e*T_ + sl];
          float wt  = wlist[e*T_ + sl];
          float g = accg[mt][r];
          float m = g / (1.f + expf(-g)) * accu[mt][r] * wt;
          hmid[(size_t)(ent & 8191)*I_ + icol] = (_Float16)m;
        }
      }
    }
  }
#undef GU_STEP
}

// ---------------- down MFMA: scr[t*8+rank, hc*128..+128) = hmid @ Wd ----
// Reg-staged transpose+convert: Wd tile [64 i][32 h] -> regs (coalesced row
// segments) -> f16 -> per-wave-private transposed LDS [32 h][64 i] (XOR
// swizzled) -> contiguous ds_read_b128 B-frags. 2-deep reg+LDS pipeline;
// issue order (A-next, W-next2, write W-next, compute) keeps prefetch alive.
// No atomics: exactly-once stores into scratch, summed by combine_k.
__global__ __launch_bounds__(256, 2) void down_k(
    const int* __restrict__ wd, const float* __restrict__ sd,
    const int* __restrict__ shwd, const float* __restrict__ shsd,
    const int* __restrict__ cnt, const int* __restrict__ tlist,
    const _Float16* __restrict__ hmid, float* __restrict__ scr)
{
  const int hc = blockIdx.x;                  // h-chunk of 128
  const int eb = blockIdx.y;
  int e, lo, hi;
  eb_decode(eb, cnt, e, lo, hi);
  if (hi <= lo) return;

  const int tid  = threadIdx.x;
  const int lane = tid & 63;
  const int wv   = tid >> 6;
  const int mr   = lane & 15;
  const int quad = lane >> 4;

  const int* wb; const float* sdp; int sib0;
  if (e < E_) { wb = wd + (size_t)e*I_*H_;        sdp = sd + e*32;  sib0 = 0; }
  else { int hf = e - E_; wb = shwd + (size_t)hf*512*H_; sdp = shsd; sib0 = hf*4; }

  __shared__ _Float16 dlds[4][2][2048];       // per-wave dbuf [32 h][64 i] f16
  _Float16* l0 = &dlds[wv][0][0];
  _Float16* l1 = &dlds[wv][1][0];

  const int h0  = hc*128 + wv*32;
  const int ig0 = lane >> 3, ig1 = ig0 + 8;   // i-groups (4 rows each)
  const int hg4 = (lane & 7) * 4;             // h-group base (4 cols)
  const int* src0 = wb + (size_t)(ig0*4)*H_ + h0 + hg4;
  const int* src1 = wb + (size_t)(ig1*4)*H_ + h0 + hg4;

  auto dload = [&](int4* w, int kt) {         // 8 coalesced int4 loads
    const size_t o = (size_t)kt * 64 * H_;
    #pragma unroll
    for (int j = 0; j < 4; j++) {
      w[j]     = *(const int4*)(src0 + o + (size_t)j*H_);
      w[4 + j] = *(const int4*)(src1 + o + (size_t)j*H_);
    }
  };

  // swizzle: 16B chunk ^= (hrow&7) ^ ((hrow>>3)&3)  (write & read sides)
  auto dwrite = [&](_Float16* lb, const int4* w, float s) {
    #pragma unroll
    for (int r = 0; r < 2; r++) {
      const int ig = r ? ig1 : ig0;
      #pragma unroll
      for (int j2 = 0; j2 < 4; j2++) {
        const int hrow = hg4 + j2;
        const int swz  = (hrow & 7) ^ ((hrow >> 3) & 3);
        h4v v = { (_Float16)((float)((&w[r*4+0].x)[j2]) * s),
                  (_Float16)((float)((&w[r*4+1].x)[j2]) * s),
                  (_Float16)((float)((&w[r*4+2].x)[j2]) * s),
                  (_Float16)((float)((&w[r*4+3].x)[j2]) * s) };
        *(h4v*)((char*)lb + hrow*128 + ((((ig >> 1) ^ swz)) << 4) + ((ig & 1) << 3)) = v;
      }
    }
  };

  f4 acc[2][4];
  auto dcompute = [&](const _Float16* lb, h8 (&A)[4][2]) {
    #pragma unroll
    for (int nf = 0; nf < 2; nf++) {
      const int hrow = nf*16 + mr;
      const int swz  = (hrow & 7) ^ ((hrow >> 3) & 3);
      #pragma unroll
      for (int ks = 0; ks < 2; ks++) {
        h8 bf = *(const h8*)((const char*)lb + hrow*128 + ((((ks << 2) + quad) ^ swz) << 4));
        #pragma unroll
        for (int mt = 0; mt < 4; mt++)
          acc[nf][mt] = __builtin_amdgcn_mfma_f32_16x16x32_f16(A[mt][ks], bf, acc[nf][mt], 0,0,0);
      }
    }
  };

#define D_STEP(KT, AU, AL, WL, WW, LBC, LBW)                                \
    if ((KT) < 7) {                                                         \
      _Pragma("unroll")                                                     \
      for (int mt = 0; mt < 4; mt++) {                                      \
        AL[mt][0] = *(const h8*)(ap[mt] + ((KT)+1)*64);                     \
        AL[mt][1] = *(const h8*)(ap[mt] + ((KT)+1)*64 + 32);                \
      }                                                                     \
    }                                                                       \
    if ((KT) < 6) dload(WL, (KT)+2);                                        \
    if ((KT) < 7) dwrite(LBW, WW, sdp[(sib0 + (((KT)+1) >> 1))*8 + hc]);    \
    dcompute(LBC, AU);

  for (int base = lo; base < hi; base += 64) {
    const _Float16* ap[4];
    #pragma unroll
    for (int mt = 0; mt < 4; mt++) {
      int sl = base + mt*16 + mr;
      int sr = (sl < hi) ? (tlist[e*T_ + sl] & 8191) : 0;
      ap[mt] = hmid + (size_t)sr*I_ + quad*8;
    }
    #pragma unroll
    for (int nf = 0; nf < 2; nf++)
      #pragma unroll
      for (int mt = 0; mt < 4; mt++) acc[nf][mt] = (f4){0.f,0.f,0.f,0.f};

    h8 avvA[4][2], avvB[4][2];
    int4 wA[8], wB[8];
    // prologue: A(0), W(0), W(1), write tile0
    #pragma unroll
    for (int mt = 0; mt < 4; mt++) {
      avvA[mt][0] = *(const h8*)(ap[mt]);
      avvA[mt][1] = *(const h8*)(ap[mt] + 32);
    }
    dload(wA, 0);
    dload(wB, 1);
    dwrite(l0, wA, sdp[sib0*8 + hc]);

    D_STEP(0, avvA, avvB, wA, wB, l0, l1)
    D_STEP(1, avvB, avvA, wB, wA, l1, l0)
    D_STEP(2, avvA, avvB, wA, wB, l0, l1)
    D_STEP(3, avvB, avvA, wB, wA, l1, l0)
    D_STEP(4, avvA, avvB, wA, wB, l0, l1)
    D_STEP(5, avvB, avvA, wB, wA, l1, l0)
    D_STEP(6, avvA, avvB, wA, wB, l0, l1)
    D_STEP(7, avvB, avvA, wB, wA, l1, l0)

    // epilogue: exactly-once stores to scratch[(t*8+rank)][hcol]
    #pragma unroll
    for (int mt = 0; mt < 4; mt++) {
      #pragma unroll
      for (int r = 0; r < 4; r++) {
        int sl = base + mt*16 + quad*4 + r;
        if (sl < hi) {
          int ent = tlist[e*T_ + sl];
          int t   = ent >> 13;
          int sr  = ent & 8191;
          int rank = (sr < 3072) ? (sr - t*6) : (6 + ((sr - 3072) >> 9));
          float* dst = scr + (size_t)(t*8 + rank)*H_ + h0 + mr;
          dst[0]  = acc[0][mt][r];
          dst[16] = acc[1][mt][r];
        }
      }
    }
  }
#undef D_STEP
}

// ---------------- combine: out[t,h] = sum_r scratch[t*8+r, h] -----------
__global__ __launch_bounds__(256) void combine_k(
    const float* __restrict__ scr, float* __restrict__ out)
{
  int i = blockIdx.x*256 + threadIdx.x;       // float4 index over T*H/4
  int t = i >> 8;                             // 256 float4 per token row
  int c = i & 255;
  const float4* base = (const float4*)(scr + (size_t)t*8*H_) + c;
  float4 s = base[0];
  #pragma unroll
  for (int r = 1; r < 8; r++) {
    float4 v = base[(size_t)r*(H_/4)];
    s.x += v.x; s.y += v.y; s.z += v.z; s.w += v.w;
  }
  ((float4*)out)[i] = s;
}

// ---------------- launch ----------------
extern "C" void kernel_launch(void* const* d_in, const int* in_sizes, int n_in,
                              void* d_out, int out_size, void* d_ws, size_t ws_size,
                              hipStream_t stream) {
  (void)in_sizes; (void)n_in; (void)ws_size; (void)out_size;
  const float* x    = (const float*)d_in[0];
  const float* gw   = (const float*)d_in[1];
  const int*   wg   = (const int*  )d_in[2];
  const float* sg   = (const float*)d_in[3];
  const int*   wu   = (const int*  )d_in[4];
  const float* su   = (const float*)d_in[5];
  const int*   wd   = (const int*  )d_in[6];
  const float* sd   = (const float*)d_in[7];
  const int*   shwg = (const int*  )d_in[8];
  const float* shsg = (const float*)d_in[9];
  const int*   shwu = (const int*  )d_in[10];
  const float* shsu = (const float*)d_in[11];
  const int*   shwd = (const int*  )d_in[12];
  const float* shsd = (const float*)d_in[13];
  float* out = (float*)d_out;

  char* ws = (char*)d_ws;
  int*      cnt   = (int*     ) ws;                                   // 66 ints
  int*      tlist = (int*     )(ws + 1024);                           // 66*512
  float*    wlist = (float*   )(ws + 1024 + 66*T_*4);                 // 66*512
  _Float16* hmid  = (_Float16*)(ws + 1024 + 2*66*T_*4);               // 4096*512 f16
  _Float16* xh    = (_Float16*)(ws + 1024 + 2*66*T_*4 + 4096*I_*2);   // 512*1024 f16
  float*    scr   = (float*   )(ws + 1024 + 2*66*T_*4 + 4096*I_*2 + T_*H_*2); // 4096*1024 f32

  hipMemsetAsync(cnt, 0, 1024, stream);
  xh_prep_k<<<T_*H_/1024, 256, 0, stream>>>(x, xh);
  router_k<<<T_, 64, 0, stream>>>(x, gw, cnt, tlist, wlist);
  pseudo_init_k<<<4, 256, 0, stream>>>(cnt, tlist, wlist);
  gateup_k<<<dim3(8, EB_), 256, 0, stream>>>(xh, wg, sg, wu, su,
                                             shwg, shsg, shwu, shsu,
                                             cnt, tlist, wlist, hmid);
  down_k<<<dim3(8, EB_), 256, 0, stream>>>(wd, sd, shwd, shsd,
                                           cnt, tlist, hmid, scr);
  combine_k<<<T_*H_/1024, 256, 0, stream>>>(scr, out);
}